// Round 3
// baseline (6996.343 us; speedup 1.0000x reference)
//
#include <hip/hip_runtime.h>
#include <hip/hip_bf16.h>

// Problem constants
#define B_   16
#define T_   16
#define H_   161
#define W_   181
#define C_   3
#define F_   21
#define F4_  84
#define CIN_ 24          // C_ + F_ combined conv input channels
#define TS   16          // spatial tile (TS x TS positions per 256-thread block)
#define TP   18          // tile + 3x3 halo
#define NPOS (TP*TP)     // 324

__device__ __forceinline__ float hsig(float x) {
  // Keras hard_sigmoid: clip(0.2x + 0.5, 0, 1)
  return fminf(fmaxf(0.2f * x + 0.5f, 0.0f), 1.0f);
}

__device__ __forceinline__ float fast_tanh(float x) {
  // tanh(x) = sign(x) * (1 - e^{-2|x|}) / (1 + e^{-2|x|}); e^{-2|x|} in (0,1] -> no overflow
  float ax = fabsf(x);
  float t = __expf(-2.0f * ax);
  float r = (1.0f - t) * __builtin_amdgcn_rcpf(1.0f + t);
  return copysignf(r, x);
}

// Weight re-layout: W2[kk][ci][f][g] = orig[kk][ci_src][g*F_+f]
// so the 4 gates of one filter form one aligned float4 (row stride 336B = 21*16B).
__global__ void prep_kernel(const float* __restrict__ k,
                            const float* __restrict__ rk,
                            const float* __restrict__ bias,
                            float* __restrict__ Wf, float* __restrict__ biasf) {
  int i = blockIdx.x * 256 + threadIdx.x;
  if (i < 9 * CIN_ * F4_) {
    int g    = i & 3;
    int rest = i >> 2;
    int f    = rest % F_;
    rest    /= F_;
    int ci   = rest % CIN_;
    int kk   = rest / CIN_;
    int oc   = g * F_ + f;   // original gate-major output-channel index
    float v;
    if (ci < C_) v = k[(kk * C_ + ci) * F4_ + oc];
    else         v = rk[(kk * F_ + (ci - C_)) * F4_ + oc];
    Wf[i] = v;
  }
  if (i < F4_) biasf[i] = bias[(i & 3) * F_ + (i >> 2)];  // b2[f*4+g]
}

#define GATES21(OP) OP(0) OP(1) OP(2) OP(3) OP(4) OP(5) OP(6) OP(7) OP(8) OP(9) \
  OP(10) OP(11) OP(12) OP(13) OP(14) OP(15) OP(16) OP(17) OP(18) OP(19) OP(20)

// One ConvLSTM time step. grid: (ceil(W/TS), ceil(H/TS), B), block: 256 = TS*TS
__global__ __launch_bounds__(256, 2) void step_kernel(
    const float* __restrict__ x,       // (B,T,H,W,C) fp32
    const float* __restrict__ Wf,      // [9][24][21][4] fp32
    const float* __restrict__ biasf,   // [21][4]
    const float* __restrict__ h_in,    // (B,H,W,F) fp32 (ignored if first)
    float* __restrict__ h_out,         // (B,H,W,F) fp32 (not written if last)
    float* __restrict__ c_buf,         // (B,H,W,F) fp32 in-place
    const float* __restrict__ mask,    // (H,W,1) fp32
    float* __restrict__ out,           // (B,H,W,F) fp32, written only if last
    int t, int first, int last) {
  __shared__ float tile[CIN_][NPOS + 1];  // channel-major: stride-1 spatial reads

  int b   = blockIdx.z;
  int by0 = blockIdx.y * TS;
  int bx0 = blockIdx.x * TS;

  // Stage input tile (with halo, zero-padded) into LDS.
  for (int i = threadIdx.x; i < CIN_ * NPOS; i += 256) {
    int ci  = i / NPOS;
    int pos = i - ci * NPOS;
    int py  = pos / TP;
    int px  = pos - py * TP;
    int gy  = by0 - 1 + py;
    int gx  = bx0 - 1 + px;
    float v = 0.0f;
    if ((unsigned)gy < (unsigned)H_ && (unsigned)gx < (unsigned)W_) {
      if (ci < C_) {
        v = x[(((size_t)(b * T_ + t) * H_ + gy) * W_ + gx) * C_ + ci];
      } else if (!first) {
        v = h_in[((size_t)(b * H_ + gy) * W_ + gx) * F_ + (ci - C_)];
      }
    }
    tile[ci][pos] = v;
  }
  __syncthreads();

  int tx = threadIdx.x & 15;
  int ty = threadIdx.x >> 4;
  int gy = by0 + ty;
  int gx = bx0 + tx;

  // 21 named float4 accumulators (one per filter; lanes = gates i,f,g,o).
  // Named scalars -> guaranteed VGPRs, no PromoteAlloca scratch spill.
  const float4* b4 = (const float4*)biasf;
#define DECL_ACC(n) float4 a##n = b4[n];
  GATES21(DECL_ACC)
#undef DECL_ACC

  for (int kk = 0; kk < 9; ++kk) {
    int ky = kk / 3;
    int kx = kk - 3 * ky;
    int pbase = (ty + ky) * TP + (tx + kx);
    const float* wbase = Wf + kk * (CIN_ * F4_);
#pragma unroll 1
    for (int ci = 0; ci < CIN_; ++ci) {
      float v = tile[ci][pbase];
      const float4* w4 = (const float4*)(wbase + ci * F4_);  // 16B-aligned, uniform
#define FMA_ACC(n) { float4 w = w4[n]; \
      a##n.x = fmaf(v, w.x, a##n.x); a##n.y = fmaf(v, w.y, a##n.y); \
      a##n.z = fmaf(v, w.z, a##n.z); a##n.w = fmaf(v, w.w, a##n.w); }
      GATES21(FMA_ACC)
#undef FMA_ACC
    }
  }

  if (gy < H_ && gx < W_) {
    size_t p  = (size_t)(b * H_ + gy) * W_ + gx;
    size_t pf = p * F_;
    float m = last ? mask[gy * W_ + gx] : 0.0f;
#define EPILOG(n) { \
    float ig = hsig(a##n.x); \
    float fg = hsig(a##n.y); \
    float gg = fast_tanh(a##n.z); \
    float og = hsig(a##n.w); \
    float cp = first ? 0.0f : c_buf[pf + n]; \
    float cn = fg * cp + ig * gg; \
    float hn = og * fast_tanh(cn); \
    c_buf[pf + n] = cn; \
    if (!last) h_out[pf + n] = hn; \
    else       out[pf + n]   = hn * m; }
    GATES21(EPILOG)
#undef EPILOG
  }
}

extern "C" void kernel_launch(void* const* d_in, const int* in_sizes, int n_in,
                              void* d_out, int out_size, void* d_ws, size_t ws_size,
                              hipStream_t stream) {
  const float* x  = (const float*)d_in[0];
  const float* k  = (const float*)d_in[1];
  const float* rk = (const float*)d_in[2];
  const float* bs = (const float*)d_in[3];
  const float* mk = (const float*)d_in[4];
  float* outF = (float*)d_out;   // (B,H,W,F) fp32 = 39.17 MB; doubles as odd-step h buffer

  char* ws = (char*)d_ws;
  float* Wf    = (float*)ws;                       // 9*24*84 = 18144 fp32
  float* biasf = Wf + 9 * CIN_ * F4_;              // 84 fp32
  size_t off = (((size_t)(9 * CIN_ * F4_ + F4_) * 4) + 255) & ~(size_t)255;
  size_t HWF = (size_t)B_ * H_ * W_ * F_;          // 9,791,376
  float* hA = (float*)(ws + off);                  // even-step h output
  float* cB = hA + HWF;                            // cell state, in-place
  // total ws use: ~78.4 MB

  prep_kernel<<<dim3((9 * CIN_ * F4_ + 255) / 256), 256, 0, stream>>>(k, rk, bs, Wf, biasf);

  dim3 grid((W_ + TS - 1) / TS, (H_ + TS - 1) / TS, B_);  // (12, 11, 16)
  for (int t = 0; t < T_; ++t) {
    // even t: read outF (h from odd t-1), write hA; odd t: read hA, write outF.
    // t=0: h_in unused (first=1). t=15 (last): h_out not written; out=d_out written.
    const float* hi = (t & 1) ? hA : outF;
    float* ho       = (t & 1) ? outF : hA;
    step_kernel<<<grid, 256, 0, stream>>>(x, Wf, biasf, hi, ho, cB, mk, outF,
                                          t, (t == 0) ? 1 : 0, (t == T_ - 1) ? 1 : 0);
  }
}

// Round 4
// 5448.931 us; speedup vs baseline: 1.2840x; 1.2840x over previous
//
#include <hip/hip_runtime.h>
#include <hip/hip_bf16.h>

// Problem constants
#define B_   16
#define T_   16
#define H_   161
#define W_   181
#define HW_  (H_*W_)     // 29141
#define C_   3
#define F_   21
#define F4_  84
#define CIN_ 24          // C_ + F_ combined conv input channels
#define FC   7           // filters per chunk
#define NCHK 3           // 3 chunks x 7 filters = 21
#define TS   16          // spatial tile (TS x TS positions per 256-thread block)
#define TP   18          // tile + 3x3 halo
#define NPOS (TP*TP)     // 324

__device__ __forceinline__ float hsig(float x) {
  return fminf(fmaxf(0.2f * x + 0.5f, 0.0f), 1.0f);
}

__device__ __forceinline__ float fast_tanh(float x) {
  float ax = fabsf(x);
  float t = __expf(-2.0f * ax);
  float r = (1.0f - t) * __builtin_amdgcn_rcpf(1.0f + t);
  return copysignf(r, x);
}

// Weight layout: Wc[chunk][kk][ci][f7][g], f7 in 0..6, g in 0..3.
// Original output channel oc = g*21 + chunk*7 + f7.
__global__ void prep_kernel(const float* __restrict__ k,
                            const float* __restrict__ rk,
                            const float* __restrict__ bias,
                            float* __restrict__ Wf, float* __restrict__ biasf) {
  int i = blockIdx.x * 256 + threadIdx.x;
  if (i < NCHK * 9 * CIN_ * FC * 4) {
    int g    = i & 3;
    int r    = i >> 2;
    int f7   = r % FC;  r /= FC;
    int ci   = r % CIN_; r /= CIN_;
    int kk   = r % 9;
    int chnk = r / 9;
    int oc   = g * F_ + chnk * FC + f7;
    float v;
    if (ci < C_) v = k[(kk * C_ + ci) * F4_ + oc];
    else         v = rk[(kk * F_ + (ci - C_)) * F4_ + oc];
    Wf[i] = v;
  }
  if (i < F4_) {
    int g    = i & 3;
    int r    = i >> 2;
    int f7   = r % FC;
    int chnk = r / FC;
    biasf[i] = bias[g * F_ + chnk * FC + f7];
  }
}

#define F7(OP) OP(0) OP(1) OP(2) OP(3) OP(4) OP(5) OP(6)

// One ConvLSTM time step. grid: (ceil(W/TS), ceil(H/TS), B), block: 256 = TS*TS
// h_in/h_out/c_buf are CHANNEL-FIRST: idx = (b*F + ch)*HW + y*W + x (coalesced).
__global__ void __launch_bounds__(256)
    __attribute__((amdgpu_waves_per_eu(2, 4)))
step_kernel(
    const float* __restrict__ x,       // (B,T,H,W,C) fp32
    const float* __restrict__ Wf,      // [3][9][24][7][4] fp32
    const float* __restrict__ biasf,   // [3][7][4]
    const float* __restrict__ h_in,    // (B,F,H,W) fp32 (ignored if first)
    float* __restrict__ h_out,         // (B,F,H,W) fp32 (not written if last)
    float* __restrict__ c_buf,         // (B,F,H,W) fp32 in-place
    const float* __restrict__ mask,    // (H,W,1) fp32
    float* __restrict__ out,           // (B,H,W,F) fp32 channel-LAST, written if last
    int t, int first, int last) {
  __shared__ float tile[CIN_][NPOS + 1];

  int b   = blockIdx.z;
  int by0 = blockIdx.y * TS;
  int bx0 = blockIdx.x * TS;

  // Stage input tile (with halo, zero-padded) into LDS. h_in channel-first -> coalesced.
  for (int i = threadIdx.x; i < CIN_ * NPOS; i += 256) {
    int ci  = i / NPOS;
    int pos = i - ci * NPOS;
    int py  = pos / TP;
    int px  = pos - py * TP;
    int gy  = by0 - 1 + py;
    int gx  = bx0 - 1 + px;
    float v = 0.0f;
    if ((unsigned)gy < (unsigned)H_ && (unsigned)gx < (unsigned)W_) {
      if (ci < C_) {
        v = x[(((size_t)(b * T_ + t) * H_ + gy) * W_ + gx) * C_ + ci];
      } else if (!first) {
        v = h_in[(size_t)(b * F_ + (ci - C_)) * HW_ + gy * W_ + gx];
      }
    }
    tile[ci][pos] = v;
  }
  __syncthreads();

  int tx = threadIdx.x & 15;
  int ty = threadIdx.x >> 4;
  int gy = by0 + ty;
  int gx = bx0 + tx;
  bool inb = (gy < H_) && (gx < W_);
  size_t q  = (size_t)b * F_ * HW_ + gy * W_ + gx;   // channel-first pixel base
  size_t pf = ((size_t)(b * H_ + gy) * W_ + gx) * F_; // channel-last pixel base (out)
  float m = (last && inb) ? mask[gy * W_ + gx] : 0.0f;

  const float4* b4 = (const float4*)biasf;

  // 3 chunks of 7 filters: only 7 float4 accumulators live at a time -> no spill.
#pragma unroll 1
  for (int chnk = 0; chnk < NCHK; ++chnk) {
#define DECL_ACC(n) float4 a##n = b4[chnk * FC + n];
    F7(DECL_ACC)
#undef DECL_ACC

#pragma unroll 1
    for (int kk = 0; kk < 9; ++kk) {
      int ky = kk / 3;
      int kx = kk - 3 * ky;
      int pbase = (ty + ky) * TP + (tx + kx);
      const float* wkk = Wf + (size_t)(chnk * 9 + kk) * (CIN_ * FC * 4);
#pragma unroll 2
      for (int ci = 0; ci < CIN_; ++ci) {
        float v = tile[ci][pbase];
        const float4* w4 = (const float4*)(wkk + ci * (FC * 4));  // uniform -> s_load
#define FMA_ACC(n) { float4 w = w4[n]; \
        a##n.x = fmaf(v, w.x, a##n.x); a##n.y = fmaf(v, w.y, a##n.y); \
        a##n.z = fmaf(v, w.z, a##n.z); a##n.w = fmaf(v, w.w, a##n.w); }
        F7(FMA_ACC)
#undef FMA_ACC
      }
    }

    if (inb) {
#define EPILOG(n) { \
      int ch = chnk * FC + n; \
      size_t idx = q + (size_t)ch * HW_; \
      float ig = hsig(a##n.x); \
      float fg = hsig(a##n.y); \
      float gg = fast_tanh(a##n.z); \
      float og = hsig(a##n.w); \
      float cp = first ? 0.0f : c_buf[idx]; \
      float cn = fg * cp + ig * gg; \
      float hn = og * fast_tanh(cn); \
      c_buf[idx] = cn; \
      if (!last) h_out[idx] = hn; \
      else       out[pf + ch] = hn * m; }
      F7(EPILOG)
#undef EPILOG
    }
  }
}

extern "C" void kernel_launch(void* const* d_in, const int* in_sizes, int n_in,
                              void* d_out, int out_size, void* d_ws, size_t ws_size,
                              hipStream_t stream) {
  const float* x  = (const float*)d_in[0];
  const float* k  = (const float*)d_in[1];
  const float* rk = (const float*)d_in[2];
  const float* bs = (const float*)d_in[3];
  const float* mk = (const float*)d_in[4];
  float* outF = (float*)d_out;   // final output; also odd-step channel-first h buffer

  char* ws = (char*)d_ws;
  float* Wf    = (float*)ws;                       // 18144 fp32
  float* biasf = Wf + 9 * CIN_ * F4_;              // 84 fp32
  size_t off = (((size_t)(9 * CIN_ * F4_ + F4_) * 4) + 255) & ~(size_t)255;
  size_t HWF = (size_t)B_ * H_ * W_ * F_;          // 9,791,376
  float* hA = (float*)(ws + off);                  // even-step h output (channel-first)
  float* cB = hA + HWF;                            // cell state (channel-first), in-place
  // total ws use ~78.4 MB

  prep_kernel<<<dim3((9 * CIN_ * F4_ + 255) / 256), 256, 0, stream>>>(k, rk, bs, Wf, biasf);

  dim3 grid((W_ + TS - 1) / TS, (H_ + TS - 1) / TS, B_);  // (12, 11, 16)
  for (int t = 0; t < T_; ++t) {
    // even t: write hA (ws); odd t: write outF. t=15 (odd, last): reads hA,
    // writes ONLY the final channel-last output into outF -> no race on d_out.
    const float* hi = (t & 1) ? hA : outF;
    float* ho       = (t & 1) ? outF : hA;
    step_kernel<<<grid, 256, 0, stream>>>(x, Wf, biasf, hi, ho, cB, mk, outF,
                                          t, (t == 0) ? 1 : 0, (t == T_ - 1) ? 1 : 0);
  }
}

// Round 5
// 3885.103 us; speedup vs baseline: 1.8008x; 1.4025x over previous
//
#include <hip/hip_runtime.h>
#include <hip/hip_bf16.h>

// Problem constants
#define B_   16
#define T_   16
#define H_   161
#define W_   181
#define HW_  (H_*W_)     // 29141
#define C_   3
#define F_   21
#define F4_  84
#define CIN_ 24          // C_ + F_ combined conv input channels
#define FC   3           // filters per chunk (weights/chunk = 10.4 KB -> scalar-cache resident)
#define NCHK 7           // 7 chunks x 3 filters = 21
#define TSX  32          // tile width  (32 px = 128B rows: coalesced global writes)
#define TSY  8           // tile height (256 threads = 32x8)
#define TPX  34          // tile + halo
#define TPY  10
#define NPOS (TPX*TPY)   // 340
#define TSTR (NPOS+1)    // padded per-channel stride (341)

__device__ __forceinline__ float hsig(float x) {
  return fminf(fmaxf(0.2f * x + 0.5f, 0.0f), 1.0f);
}

__device__ __forceinline__ float fast_tanh(float x) {
  float ax = fabsf(x);
  float t = __expf(-2.0f * ax);
  float r = (1.0f - t) * __builtin_amdgcn_rcpf(1.0f + t);
  return copysignf(r, x);
}

// Weight layout: Wf[chunk][kk][ci][f3][g]; original output channel oc = g*21 + chunk*3 + f3.
__global__ void prep_kernel(const float* __restrict__ k,
                            const float* __restrict__ rk,
                            const float* __restrict__ bias,
                            float* __restrict__ Wf, float* __restrict__ biasf) {
  int i = blockIdx.x * 256 + threadIdx.x;
  if (i < NCHK * 9 * CIN_ * FC * 4) {
    int g    = i & 3;
    int r    = i >> 2;
    int f3   = r % FC;   r /= FC;
    int ci   = r % CIN_; r /= CIN_;
    int kk   = r % 9;
    int chnk = r / 9;
    int oc   = g * F_ + chnk * FC + f3;
    float v;
    if (ci < C_) v = k[(kk * C_ + ci) * F4_ + oc];
    else         v = rk[(kk * F_ + (ci - C_)) * F4_ + oc];
    Wf[i] = v;
  }
  if (i < F4_) {
    int g    = i & 3;
    int r    = i >> 2;
    int f3   = r % FC;
    int chnk = r / FC;
    biasf[i] = bias[g * F_ + chnk * FC + f3];
  }
}

#define F3(OP) OP(0) OP(1) OP(2)

// One ConvLSTM time step. grid: (ceil(W/32), ceil(H/8), B), block 256 = 32x8.
// h_in/h_out/c_buf CHANNEL-FIRST: idx = (b*F + ch)*HW + y*W + x.
// LDS tile TRANSPOSED: tile[ci][px*TPY + py] -> all wave reads are uniform 2-way
// bank aliasing (free on CDNA4).
__global__ void __launch_bounds__(256) step_kernel(
    const float* __restrict__ x,       // (B,T,H,W,C) fp32
    const float* __restrict__ Wf,      // [7][9][24][3][4] fp32
    const float* __restrict__ biasf,   // [7][3][4]
    const float* __restrict__ h_in,    // (B,F,H,W) fp32 (ignored if first)
    float* __restrict__ h_out,         // (B,F,H,W) fp32 (not written if last)
    float* __restrict__ c_buf,         // (B,F,H,W) fp32 in-place
    const float* __restrict__ mask,    // (H,W,1) fp32
    float* __restrict__ out,           // (B,H,W,F) fp32 channel-LAST, written if last
    int t, int first, int last) {
  __shared__ float tile[CIN_][TSTR];   // 24*341*4 = 32.7 KB -> 4 blocks/CU

  int b   = blockIdx.z;
  int by0 = blockIdx.y * TSY;
  int bx0 = blockIdx.x * TSX;

  // Stage input tile (halo, zero-padded). Decode pos px-minor (coalesced global
  // reads along x); store transposed at px*TPY+py.
  for (int i = threadIdx.x; i < CIN_ * NPOS; i += 256) {
    int ci  = i / NPOS;
    int pos = i - ci * NPOS;
    int px  = pos % TPX;
    int py  = pos / TPX;
    int gy  = by0 - 1 + py;
    int gx  = bx0 - 1 + px;
    float v = 0.0f;
    if ((unsigned)gy < (unsigned)H_ && (unsigned)gx < (unsigned)W_) {
      if (ci < C_) {
        v = x[(((size_t)(b * T_ + t) * H_ + gy) * W_ + gx) * C_ + ci];
      } else if (!first) {
        v = h_in[(size_t)(b * F_ + (ci - C_)) * HW_ + gy * W_ + gx];
      }
    }
    tile[ci][px * TPY + py] = v;
  }
  __syncthreads();

  int tx = threadIdx.x & 31;   // 0..31
  int ty = threadIdx.x >> 5;   // 0..7
  int gy = by0 + ty;
  int gx = bx0 + tx;
  bool inb = (gy < H_) && (gx < W_);
  size_t q  = (size_t)b * F_ * HW_ + gy * W_ + gx;    // channel-first pixel base
  size_t pf = ((size_t)(b * H_ + gy) * W_ + gx) * F_; // channel-last pixel base
  float m = (last && inb) ? mask[gy * W_ + gx] : 0.0f;

  const float4* b4 = (const float4*)biasf;
  int tbase = tx * TPY + ty;   // transposed (px,py) base for this thread

  // 7 chunks of 3 filters: 3 float4 accumulators live -> ~12 acc VGPRs, no spill.
#pragma unroll 1
  for (int chnk = 0; chnk < NCHK; ++chnk) {
#define DECL_ACC(n) float4 a##n = b4[chnk * FC + n];
    F3(DECL_ACC)
#undef DECL_ACC

#pragma unroll 1
    for (int kk = 0; kk < 9; ++kk) {
      int ky = kk / 3;
      int kx = kk - 3 * ky;
      int pb = tbase + kx * TPY + ky;                  // + ci*TSTR inside
      const float* wkk = Wf + (size_t)(chnk * 9 + kk) * (CIN_ * FC * 4);
#pragma unroll 6
      for (int ci = 0; ci < CIN_; ++ci) {
        float v = tile[ci][pb];                        // ds_read_b32, 2-way free
        const float4* w4 = (const float4*)(wkk + ci * (FC * 4));  // uniform -> s_load
#define FMA_ACC(n) { float4 w = w4[n]; \
        a##n.x = fmaf(v, w.x, a##n.x); a##n.y = fmaf(v, w.y, a##n.y); \
        a##n.z = fmaf(v, w.z, a##n.z); a##n.w = fmaf(v, w.w, a##n.w); }
        F3(FMA_ACC)
#undef FMA_ACC
      }
    }

    if (inb) {
#define EPILOG(n) { \
      int ch = chnk * FC + n; \
      size_t idx = q + (size_t)ch * HW_; \
      float ig = hsig(a##n.x); \
      float fg = hsig(a##n.y); \
      float gg = fast_tanh(a##n.z); \
      float og = hsig(a##n.w); \
      float cp = first ? 0.0f : c_buf[idx]; \
      float cn = fg * cp + ig * gg; \
      float hn = og * fast_tanh(cn); \
      c_buf[idx] = cn; \
      if (!last) h_out[idx] = hn; \
      else       out[pf + ch] = hn * m; }
      F3(EPILOG)
#undef EPILOG
    }
  }
}

extern "C" void kernel_launch(void* const* d_in, const int* in_sizes, int n_in,
                              void* d_out, int out_size, void* d_ws, size_t ws_size,
                              hipStream_t stream) {
  const float* x  = (const float*)d_in[0];
  const float* k  = (const float*)d_in[1];
  const float* rk = (const float*)d_in[2];
  const float* bs = (const float*)d_in[3];
  const float* mk = (const float*)d_in[4];
  float* outF = (float*)d_out;   // final output; also odd-step channel-first h buffer

  char* ws = (char*)d_ws;
  float* Wf    = (float*)ws;                       // 18144 fp32
  float* biasf = Wf + NCHK * 9 * CIN_ * FC * 4;    // 84 fp32
  size_t off = (((size_t)(NCHK * 9 * CIN_ * FC * 4 + F4_) * 4) + 255) & ~(size_t)255;
  size_t HWF = (size_t)B_ * H_ * W_ * F_;          // 9,791,376
  float* hA = (float*)(ws + off);                  // even-step h (channel-first)
  float* cB = hA + HWF;                            // cell state (channel-first)
  // total ws use ~78.4 MB

  prep_kernel<<<dim3((NCHK * 9 * CIN_ * FC * 4 + 255) / 256), 256, 0, stream>>>(
      k, rk, bs, Wf, biasf);

  dim3 grid((W_ + TSX - 1) / TSX, (H_ + TSY - 1) / TSY, B_);  // (6, 21, 16)
  for (int t = 0; t < T_; ++t) {
    // even t: write hA (ws); odd t: write outF. t=15 (odd, last): reads hA,
    // writes ONLY the final channel-last output into outF -> no race on d_out.
    const float* hi = (t & 1) ? hA : outF;
    float* ho       = (t & 1) ? outF : hA;
    step_kernel<<<grid, 256, 0, stream>>>(x, Wf, biasf, hi, ho, cB, mk, outF,
                                          t, (t == 0) ? 1 : 0, (t == T_ - 1) ? 1 : 0);
  }
}